// Round 3
// baseline (992.892 us; speedup 1.0000x reference)
//
#include <hip/hip_runtime.h>
#include <math.h>

#define HOP 441
#define NMEL 80

__device__ __forceinline__ float2 cmulf(float2 a, float2 b) {
    return make_float2(a.x * b.x - a.y * b.y, a.x * b.y + a.y * b.x);
}
__device__ __forceinline__ float2 cadd(float2 a, float2 b) {
    return make_float2(a.x + b.x, a.y + b.y);
}
__device__ __forceinline__ float2 csub(float2 a, float2 b) {
    return make_float2(a.x - b.x, a.y - b.y);
}
// LDS anti-bank-conflict padding: one extra float2 per 16
__device__ __forceinline__ int padi(int i) { return i + (i >> 4); }

// radix-8 DFT in registers + stage twiddles w_r = tw[r*tb] (products for r=3,5,6,7)
__device__ __forceinline__ void dft8_tw(float2 (&z)[8], const float2* __restrict__ tw, int tb) {
    const float C8 = 0.70710678118654752f;
    // E = DFT4(z0,z2,z4,z6), O = DFT4(z1,z3,z5,z7)
    float2 s0 = cadd(z[0], z[4]), d0 = csub(z[0], z[4]);
    float2 s1 = cadd(z[2], z[6]), d1 = csub(z[2], z[6]);
    float2 E0 = cadd(s0, s1), E2 = csub(s0, s1);
    float2 E1 = make_float2(d0.x + d1.y, d0.y - d1.x);   // d0 - i*d1
    float2 E3 = make_float2(d0.x - d1.y, d0.y + d1.x);   // d0 + i*d1
    float2 t0 = cadd(z[1], z[5]), e0 = csub(z[1], z[5]);
    float2 t1 = cadd(z[3], z[7]), e1 = csub(z[3], z[7]);
    float2 O0 = cadd(t0, t1), O2 = csub(t0, t1);
    float2 O1 = make_float2(e0.x + e1.y, e0.y - e1.x);
    float2 O3 = make_float2(e0.x - e1.y, e0.y + e1.x);
    float2 W1O1 = make_float2(C8 * (O1.x + O1.y), C8 * (O1.y - O1.x));   // w8^1*O1
    float2 MiO2 = make_float2(O2.y, -O2.x);                               // -i*O2
    float2 W3O3 = make_float2(C8 * (O3.y - O3.x), -C8 * (O3.x + O3.y));  // w8^3*O3
    z[0] = cadd(E0, O0);   z[4] = csub(E0, O0);
    z[1] = cadd(E1, W1O1); z[5] = csub(E1, W1O1);
    z[2] = cadd(E2, MiO2); z[6] = csub(E2, MiO2);
    z[3] = cadd(E3, W3O3); z[7] = csub(E3, W3O3);
    const float2 w1 = tw[tb];
    const float2 w2 = tw[2 * tb];
    const float2 w4 = tw[4 * tb];
    const float2 w3 = cmulf(w1, w2);
    const float2 w5 = cmulf(w1, w4);
    const float2 w6 = cmulf(w2, w4);
    const float2 w7 = cmulf(w3, w4);
    z[1] = cmulf(z[1], w1); z[2] = cmulf(z[2], w2); z[3] = cmulf(z[3], w3);
    z[4] = cmulf(z[4], w4); z[5] = cmulf(z[5], w5); z[6] = cmulf(z[6], w6);
    z[7] = cmulf(z[7], w7);
}

// One workgroup = FPB frames of one batch row, one FFT size.
// FFT: register radix-8 gather Stockham, 3 r8 stages (m=1,8,64) + twiddle-free
// radix-(N/512) tail. CONC = 512/(N/8) frames in flight. Single padded LDS
// buffer, 2 barriers per exchange. Power spectra bf16 in LDS [k][frame];
// mel matrix read once per WG.
template<int FLEN, int FPB, int SZI>
__global__ __launch_bounds__(512)
void spect_kernel(const float* __restrict__ x, const float* __restrict__ win,
                  const float* __restrict__ mel, float* __restrict__ out,
                  int T, int n0) {
    constexpr int N     = FLEN / 2;                 // complex FFT size
    constexpr int K     = N + 1;                    // rfft bins
    constexpr int KP    = N + 8;
    constexpr int HALF  = FLEN / 2;
    constexpr int NT    = 512;
    constexpr int TPF   = N / 8;                    // threads per frame
    constexpr int CONC  = NT / TPF;                 // frames in flight
    constexpr int FR    = N / 512;                  // final radix: 1, 2, 4
    constexpr int PADSZ = N + (N >> 4);

    __shared__ union ShU {
        float2 fbuf[CONC * PADSZ];                  // FFT working set (padded)
        float  res[FPB * NMEL];                     // mel results (reused after FFTs)
    } sh;
    __shared__ float2 tw[N / 2];
    __shared__ uint4 pows4[(KP * FPB) / 8];         // bf16 power, layout [k][frame]
    unsigned short* pows = (unsigned short*)pows4;

    const int tid   = threadIdx.x;
    const int sub   = tid / TPF;
    const int ulane = tid & (TPF - 1);
    const int b     = blockIdx.y;
    const int t0    = blockIdx.x * FPB;

    // twiddle table: tw[q] = exp(-2*pi*i*q/N), q in [0, N/2)
    for (int i = tid; i < N / 2; i += NT) {
        float s, c;
        sincosf(-6.283185307179586f * (float)i / (float)N, &s, &c);
        tw[i] = make_float2(c, s);
    }

    const float* xb = x + (size_t)b * (size_t)T;
    const int Tp = T + HALF;
    float2* buf = sh.fbuf + sub * PADSZ;

    for (int fi = 0; fi < FPB; fi += CONC) {
        __syncthreads();   // buf free (prev unpack done); tw ready on iter 0

        const int t = t0 + fi + sub;
        const bool valid = (t < n0);
        const int start = HOP * t;
        int pad = start + FLEN - Tp; if (pad < 0) pad = 0;
        const int base = start - pad - HALF;

        float2 z[8];
        // stage m=1 inputs straight from global (windowed, masked)
        #pragma unroll
        for (int q = 0; q < 8; ++q) {
            const int i  = ulane + q * (N / 8);
            const int j0 = 2 * i;
            const float2 wv = ((const float2*)win)[i];
            const int xi0 = base + j0;
            const int xi1 = xi0 + 1;
            float v0 = (valid && j0 >= pad && xi0 >= 0) ? xb[xi0] * wv.x : 0.0f;
            float v1 = (valid && j0 + 1 >= pad && xi1 >= 0) ? xb[xi1] * wv.y : 0.0f;
            z[q] = make_float2(v0, v1);
        }

        // ---- stage m=1 ----
        dft8_tw(z, tw, ulane);
        #pragma unroll
        for (int r = 0; r < 8; ++r) buf[padi(8 * ulane + r)] = z[r];
        __syncthreads();
        #pragma unroll
        for (int q = 0; q < 8; ++q) z[q] = buf[padi(ulane + q * (N / 8))];
        __syncthreads();

        // ---- stage m=8 ----
        dft8_tw(z, tw, ulane & ~7);
        {
            const int dbase = (ulane & 7) + ((ulane >> 3) << 6);
            #pragma unroll
            for (int r = 0; r < 8; ++r) buf[padi(dbase + (r << 3))] = z[r];
        }
        __syncthreads();
        #pragma unroll
        for (int q = 0; q < 8; ++q) z[q] = buf[padi(ulane + q * (N / 8))];
        __syncthreads();

        // ---- stage m=64 ----
        dft8_tw(z, tw, ulane & ~63);
        {
            const int dbase = (ulane & 63) + ((ulane >> 6) << 9);
            #pragma unroll
            for (int r = 0; r < 8; ++r) buf[padi(dbase + (r << 6))] = z[r];
        }
        __syncthreads();

        // ---- twiddle-free tail stage (m = 512) ----
        if constexpr (FR == 4) {          // N = 2048: 2 radix-4 butterflies/thread
            #pragma unroll
            for (int w = 0; w < 2; ++w) {
                const int u = ulane + w * TPF;
                #pragma unroll
                for (int q = 0; q < 4; ++q) z[4 * w + q] = buf[padi(u + q * (N / 4))];
            }
            __syncthreads();
            #pragma unroll
            for (int w = 0; w < 2; ++w) {
                const int u = ulane + w * TPF;
                const float2 A = z[4 * w], C = z[4 * w + 1], B = z[4 * w + 2], D = z[4 * w + 3];
                const float2 P = cadd(A, B), Q = csub(A, B);
                const float2 R = cadd(C, D), S = csub(C, D);
                buf[padi(u)]                = cadd(P, R);
                buf[padi(u + (N / 4))]      = make_float2(Q.x + S.y, Q.y - S.x);  // Q - iS
                buf[padi(u + 2 * (N / 4))]  = csub(P, R);
                buf[padi(u + 3 * (N / 4))]  = make_float2(Q.x - S.y, Q.y + S.x);  // Q + iS
            }
            __syncthreads();
        } else if constexpr (FR == 2) {   // N = 1024: 4 radix-2 butterflies/thread
            #pragma unroll
            for (int w = 0; w < 4; ++w) {
                const int u = ulane + w * TPF;
                z[2 * w]     = buf[padi(u)];
                z[2 * w + 1] = buf[padi(u + (N / 2))];
            }
            __syncthreads();
            #pragma unroll
            for (int w = 0; w < 4; ++w) {
                const int u = ulane + w * TPF;
                buf[padi(u)]           = cadd(z[2 * w], z[2 * w + 1]);
                buf[padi(u + (N / 2))] = csub(z[2 * w], z[2 * w + 1]);
            }
            __syncthreads();
        }

        // unpack rfft from half-size complex FFT, power, store bf16 (truncated)
        for (int k = ulane; k < K; k += TPF) {
            const float2 Zk = buf[padi(k & (N - 1))];          // k==N wraps to Z[0]
            const float2 Zn = buf[padi((N - k) & (N - 1))];
            const float Er = 0.5f * (Zk.x + Zn.x);
            const float Ei = 0.5f * (Zk.y - Zn.y);
            const float Dr = Zk.x - Zn.x;
            const float Di = Zk.y + Zn.y;
            const float Or = 0.5f * Di;                        // O = -i/2 * (Zk - conj(Zn))
            const float Oi = -0.5f * Dr;
            float sw, cw;
            __sincosf(3.14159265358979f * (float)k / (float)N, &sw, &cw);
            const float Xr = Er + cw * Or + sw * Oi;
            const float Xi = Ei + cw * Oi - sw * Or;
            const float p = Xr * Xr + Xi * Xi;
            pows[k * FPB + fi + sub] = (unsigned short)(__float_as_uint(p) >> 16);
        }
        // loop-top barrier protects buf before next group's writes
    }
    __syncthreads();   // pows complete; fbuf free for res

    // ---- mel: out[fi][m] = sum_k pow[k][fi] * mel[k][m] ----
    float* res = sh.res;
    for (int i = tid; i < FPB * NMEL; i += NT) res[i] = 0.0f;
    __syncthreads();

    constexpr int NCH = 25;                    // k-chunks
    constexpr int CH  = (K + NCH - 1) / NCH;
    if (tid < NCH * 20) {
        const int g  = tid % 20;               // m-group: mel bins 4g..4g+3
        const int c  = tid / 20;               // k-chunk
        const int k0 = c * CH;
        const int k1 = (k0 + CH < K) ? (k0 + CH) : K;
        float acc[FPB][4];
        #pragma unroll
        for (int f2 = 0; f2 < FPB; ++f2) {
            acc[f2][0] = 0.f; acc[f2][1] = 0.f; acc[f2][2] = 0.f; acc[f2][3] = 0.f;
        }
        for (int k = k0; k < k1; ++k) {
            const float4 mr = *(const float4*)(mel + (size_t)k * NMEL + 4 * g);
            const uint4* prow = (const uint4*)(pows + k * FPB);
#define ACC2(W32, BASE) { \
            const float p0 = __uint_as_float((W32) << 16); \
            const float p1 = __uint_as_float((W32) & 0xFFFF0000u); \
            acc[BASE][0] += p0 * mr.x; acc[BASE][1] += p0 * mr.y; \
            acc[BASE][2] += p0 * mr.z; acc[BASE][3] += p0 * mr.w; \
            acc[(BASE)+1][0] += p1 * mr.x; acc[(BASE)+1][1] += p1 * mr.y; \
            acc[(BASE)+1][2] += p1 * mr.z; acc[(BASE)+1][3] += p1 * mr.w; }
            {
                const uint4 pv = prow[0];
                ACC2(pv.x, 0) ACC2(pv.y, 2) ACC2(pv.z, 4) ACC2(pv.w, 6)
            }
            if constexpr (FPB == 16) {
                const uint4 pv = prow[1];
                ACC2(pv.x, 8) ACC2(pv.y, 10) ACC2(pv.z, 12) ACC2(pv.w, 14)
            }
#undef ACC2
        }
        #pragma unroll
        for (int f2 = 0; f2 < FPB; ++f2) {
            #pragma unroll
            for (int mi = 0; mi < 4; ++mi) {
                atomicAdd(&res[f2 * NMEL + 4 * g + mi], acc[f2][mi]);
            }
        }
    }
    __syncthreads();

    const size_t outbase = (size_t)b * (size_t)n0 * NMEL * 3;
    for (int i = tid; i < FPB * NMEL; i += NT) {
        const int f2 = i / NMEL;
        const int m  = i % NMEL;
        const int t  = t0 + f2;
        if (t < n0) {
            out[outbase + ((size_t)t * NMEL + m) * 3 + SZI] = logf(res[i] + 1e-16f);
        }
    }
}

extern "C" void kernel_launch(void* const* d_in, const int* in_sizes, int n_in,
                              void* d_out, int out_size, void* d_ws, size_t ws_size,
                              hipStream_t stream) {
    const float* x  = (const float*)d_in[0];
    const float* w1 = (const float*)d_in[1];
    const float* m1 = (const float*)d_in[2];
    const float* w2 = (const float*)d_in[3];
    const float* m2 = (const float*)d_in[4];
    const float* w4 = (const float*)d_in[5];
    const float* m4 = (const float*)d_in[6];
    float* out = (float*)d_out;

    const int B  = 8;
    const int T  = in_sizes[0] / B;
    const int n0 = (T + 512 + 440) / 441;   // ceil((T + 1024/2) / 441)

    spect_kernel<1024,  8, 0><<<dim3((n0 +  7) /  8, B), 512, 0, stream>>>(x, w1, m1, out, T, n0);
    spect_kernel<2048, 16, 1><<<dim3((n0 + 15) / 16, B), 512, 0, stream>>>(x, w2, m2, out, T, n0);
    spect_kernel<4096,  8, 2><<<dim3((n0 +  7) /  8, B), 512, 0, stream>>>(x, w4, m4, out, T, n0);
}